// Round 2
// baseline (663.129 us; speedup 1.0000x reference)
//
#include <hip/hip_runtime.h>

#define NN 65536
#define PP 64
#define HH 64
#define FINN 16
#define NG 1024
#define EPSF 1e-5f
#define C1 0.0625f

typedef short bf16x8 __attribute__((ext_vector_type(8)));
typedef short s16x4 __attribute__((ext_vector_type(4)));
typedef float f32x4 __attribute__((ext_vector_type(4)));
typedef unsigned short u16;

#define MFMA(a, b, c) __builtin_amdgcn_mfma_f32_16x16x32_bf16(a, b, c, 0, 0, 0)

__device__ __forceinline__ u16 f2bf(float x) {
  union { float f; unsigned u; } v; v.f = x; return (u16)(v.u >> 16);
}
__device__ __forceinline__ float bf2f(u16 h) {
  union { float f; unsigned u; } v; v.u = ((unsigned)h) << 16; return v.f;
}
__device__ __forceinline__ void split2(float x, u16& h, u16& l) {
  h = f2bf(x); l = f2bf(x - bf2f(h));
}
// swizzled index into a 64x64 u16 LDS tile: 16B granules XOR'd by row&7
__device__ __forceinline__ int XIDX(int r, int c) {
  return r * 64 + ((((c >> 3) ^ (r & 7)) << 3) | (c & 7));
}

// Build local adjacency (multiplicity) for this graph into Adj (bf16, swizzled).
// One lane per dst row; counts are exact integers <=16 in bf16.
__device__ __forceinline__ void build_adj(const int* __restrict__ src, int g,
                                          int r, u16* Adj) {
  bf16x8 z = {0, 0, 0, 0, 0, 0, 0, 0};
#pragma unroll
  for (int q = 0; q < 8; q++) *(bf16x8*)&Adj[r * 64 + q * 8] = z;
  const int4* s4 = (const int4*)(src + (size_t)g * 1024 + (size_t)r * 16);
  int4 a0 = s4[0], a1 = s4[1], a2 = s4[2], a3 = s4[3];
  int b0 = g * 64;
  int ss[16] = {a0.x - b0, a0.y - b0, a0.z - b0, a0.w - b0,
                a1.x - b0, a1.y - b0, a1.z - b0, a1.w - b0,
                a2.x - b0, a2.y - b0, a2.z - b0, a2.w - b0,
                a3.x - b0, a3.y - b0, a3.z - b0, a3.w - b0};
#pragma unroll
  for (int e = 0; e < 16; e++) {
    int idx = XIDX(r, ss[e]);
    Adj[idx] = f2bf(bf2f(Adj[idx]) + 1.0f);
  }
}

// BN+ReLU stage from global pre-BN y into node-major (and optionally
// ch-major) split-bf16 LDS tiles. Thread covers node t>>2, ch (t&3)*16..+15.
__device__ __forceinline__ void stage_bn(
    const float* __restrict__ y_in, const float* __restrict__ stats_in,
    const float* __restrict__ gam, const float* __restrict__ bet, int g, int t,
    u16* NMh, u16* NMl, u16* CMh, u16* CMl) {
  const float inv = 1.0f / (float)NN;
  int n = t >> 2, c0 = (t & 3) * 16;
  const float* yr = y_in + ((size_t)(g * 64 + n)) * 64 + c0;
  u16 hh[16], ll[16];
#pragma unroll
  for (int q = 0; q < 4; q++) {
    float4 v = ((const float4*)yr)[q];
#pragma unroll
    for (int k = 0; k < 4; k++) {
      int c = c0 + q * 4 + k;
      float s1 = stats_in[c], s2 = stats_in[64 + c];
      float mu = s1 * inv;
      float var = fmaf(s2, inv, -mu * mu);
      float sc = gam[c] * rsqrtf(var + EPSF);
      float sh = fmaf(-mu, sc, bet[c]);
      float x = (k == 0) ? v.x : (k == 1) ? v.y : (k == 2) ? v.z : v.w;
      float h = fmaxf(fmaf(sc, x, sh), 0.f);
      split2(h, hh[q * 4 + k], ll[q * 4 + k]);
    }
  }
  bf16x8 vh0, vh1, vl0, vl1;
#pragma unroll
  for (int k = 0; k < 8; k++) {
    vh0[k] = (short)hh[k]; vl0[k] = (short)ll[k];
    vh1[k] = (short)hh[8 + k]; vl1[k] = (short)ll[8 + k];
  }
  *(bf16x8*)&NMh[XIDX(n, c0)] = vh0;
  *(bf16x8*)&NMh[XIDX(n, c0 + 8)] = vh1;
  *(bf16x8*)&NMl[XIDX(n, c0)] = vl0;
  *(bf16x8*)&NMl[XIDX(n, c0 + 8)] = vl1;
  if (CMh) {
#pragma unroll
    for (int k = 0; k < 16; k++) {
      CMh[XIDX(c0 + k, n)] = hh[k];
      CMl[XIDX(c0 + k, n)] = ll[k];
    }
  }
}

// Epilogue: add bias, store Yt frags as float4, emit BN stats.
__device__ __forceinline__ void epilogue(f32x4 a0, f32x4 a1, f32x4 a2, f32x4 a3,
                                         const float* __restrict__ bias, int g,
                                         int w, int ml, int kq,
                                         float* __restrict__ y_out,
                                         float* __restrict__ stats_out) {
  float4 bb = *(const float4*)(bias + w * 16 + kq * 4);
  float s1[4] = {0, 0, 0, 0}, s2[4] = {0, 0, 0, 0};
#pragma unroll
  for (int nt = 0; nt < 4; nt++) {
    f32x4 A = (nt == 0) ? a0 : (nt == 1) ? a1 : (nt == 2) ? a2 : a3;
    float4 yv;
    yv.x = A[0] + bb.x; yv.y = A[1] + bb.y;
    yv.z = A[2] + bb.z; yv.w = A[3] + bb.w;
    int n = nt * 16 + ml;
    *(float4*)(y_out + ((size_t)(g * 64 + n)) * 64 + w * 16 + kq * 4) = yv;
    s1[0] += yv.x; s2[0] += yv.x * yv.x;
    s1[1] += yv.y; s2[1] += yv.y * yv.y;
    s1[2] += yv.z; s2[2] += yv.z * yv.z;
    s1[3] += yv.w; s2[3] += yv.w * yv.w;
  }
#pragma unroll
  for (int i = 0; i < 4; i++) {
#pragma unroll
    for (int off = 1; off < 16; off <<= 1) {
      s1[i] += __shfl_xor(s1[i], off, 64);
      s2[i] += __shfl_xor(s2[i], off, 64);
    }
  }
  if (ml == 0) {
    int c = w * 16 + kq * 4;
#pragma unroll
    for (int i = 0; i < 4; i++) {
      atomicAdd(stats_out + c + i, s1[i]);
      atomicAdd(stats_out + 64 + c + i, s2[i]);
    }
  }
}

// ---------------------------------------------------------------------------
// cheb layer, CI=64 (layers 3 & 5). W is folded: [W0-W2 | W1 | W2], K=192.
// ---------------------------------------------------------------------------
__global__ __launch_bounds__(256, 2) void k_cheb64(
    const float* __restrict__ y_in, const float* __restrict__ stats_in,
    const float* __restrict__ gam, const float* __restrict__ bet,
    const int* __restrict__ src, const u16* __restrict__ wh,
    const u16* __restrict__ wl, const float* __restrict__ bias,
    float* __restrict__ y_out, float* __restrict__ stats_out) {
  __shared__ u16 NMh[4096], NMl[4096], C0h[4096], C0l[4096], C1h[4096],
      C1l[4096], Adj[4096];
  const int t = threadIdx.x, g = blockIdx.x;
  const int L = t & 63;
  const int w = __builtin_amdgcn_readfirstlane(t >> 6);
  const int ml = L & 15, kq = L >> 4;

  stage_bn(y_in, stats_in, gam, bet, g, t, NMh, NMl, C0h, C0l);
  if (w == 3) build_adj(src, g, L, Adj);
  __syncthreads();

  f32x4 acc0 = {0, 0, 0, 0}, acc1 = {0, 0, 0, 0}, acc2 = {0, 0, 0, 0},
        acc3 = {0, 0, 0, 0};
  const u16* whp = wh + (size_t)(w * 16 + ml) * 192 + kq * 8;
  const u16* wlp = wl + (size_t)(w * 16 + ml) * 192 + kq * 8;

  auto yacc = [&](int kbase) {
#pragma unroll
    for (int kt = 0; kt < 2; kt++) {
      bf16x8 ah = *(const bf16x8*)(whp + kbase + kt * 32);
      bf16x8 al = *(const bf16x8*)(wlp + kbase + kt * 32);
      int kk = kt * 32 + kq * 8;
#pragma unroll
      for (int nt = 0; nt < 4; nt++) {
        int node = nt * 16 + ml;
        bf16x8 bh = *(const bf16x8*)&NMh[XIDX(node, kk)];
        bf16x8 bl = *(const bf16x8*)&NMl[XIDX(node, kk)];
        f32x4& A = (nt == 0) ? acc0 : (nt == 1) ? acc1 : (nt == 2) ? acc2 : acc3;
        A = MFMA(ah, bh, A);
        A = MFMA(al, bh, A);
        A = MFMA(ah, bl, A);
      }
    }
  };

  auto lap = [&](const u16* Bh, const u16* Bl, float scale, u16* oCh, u16* oCl) {
    f32x4 l0 = {0, 0, 0, 0}, l1 = {0, 0, 0, 0}, l2 = {0, 0, 0, 0},
          l3 = {0, 0, 0, 0};
#pragma unroll
    for (int kt = 0; kt < 2; kt++) {
      int kk = kt * 32 + kq * 8;
      bf16x8 aa = *(const bf16x8*)&Adj[XIDX(w * 16 + ml, kk)];
#pragma unroll
      for (int nt = 0; nt < 4; nt++) {
        bf16x8 bh = *(const bf16x8*)&Bh[XIDX(nt * 16 + ml, kk)];
        bf16x8 bl = *(const bf16x8*)&Bl[XIDX(nt * 16 + ml, kk)];
        f32x4& A = (nt == 0) ? l0 : (nt == 1) ? l1 : (nt == 2) ? l2 : l3;
        A = MFMA(aa, bh, A);
        A = MFMA(aa, bl, A);
      }
    }
    int r0 = w * 16 + kq * 4;
#pragma unroll
    for (int nt = 0; nt < 4; nt++) {
      f32x4 A = (nt == 0) ? l0 : (nt == 1) ? l1 : (nt == 2) ? l2 : l3;
      int c = nt * 16 + ml;
      u16 hh[4], ll[4];
#pragma unroll
      for (int i = 0; i < 4; i++) {
        split2(A[i] * scale, hh[i], ll[i]);
        NMh[XIDX(r0 + i, c)] = hh[i];
        NMl[XIDX(r0 + i, c)] = ll[i];
      }
      if (oCh) {
        s16x4 vh, vl;
#pragma unroll
        for (int i = 0; i < 4; i++) { vh[i] = (short)hh[i]; vl[i] = (short)ll[i]; }
        *(s16x4*)&oCh[XIDX(c, r0)] = vh;
        *(s16x4*)&oCl[XIDX(c, r0)] = vl;
      }
    }
  };

  yacc(0);                 // X0 against W0' = W0 - W2
  __syncthreads();
  lap(C0h, C0l, -C1, C1h, C1l);       // X1 = -C1*Adj*X0 -> NM, CM1
  __syncthreads();
  yacc(64);                // X1 against W1
  __syncthreads();
  lap(C1h, C1l, -2.0f * C1, nullptr, nullptr);  // Z2 = -2C1*Adj*X1 -> NM
  __syncthreads();
  yacc(128);               // Z2 against W2
  epilogue(acc0, acc1, acc2, acc3, bias, g, w, ml, kq, y_out, stats_out);
}

// ---------------------------------------------------------------------------
// econv: y[n] = T[n] + P[n] + tb + pb - min_src T[src]
// ---------------------------------------------------------------------------
__global__ __launch_bounds__(256, 4) void k_econv(
    const float* __restrict__ y_in, const float* __restrict__ stats_in,
    const float* __restrict__ gam, const float* __restrict__ bet,
    const int* __restrict__ src, const u16* __restrict__ twh,
    const u16* __restrict__ twl, const u16* __restrict__ pwh,
    const u16* __restrict__ pwl, const float* __restrict__ tb,
    const float* __restrict__ pb, float* __restrict__ y_out,
    float* __restrict__ stats_out) {
  __shared__ u16 NMh[4096], NMl[4096];
  __shared__ float Tf[64 * 68];
  __shared__ unsigned sW[256];
  const int t = threadIdx.x, g = blockIdx.x;
  const int L = t & 63;
  const int w = __builtin_amdgcn_readfirstlane(t >> 6);
  const int ml = L & 15, kq = L >> 4;
  {
    const int4* s4 = (const int4*)(src + (size_t)g * 1024);
    int4 v = s4[t];
    int b0 = g * 64;
    sW[t] = (unsigned)(v.x - b0) | ((unsigned)(v.y - b0) << 8) |
            ((unsigned)(v.z - b0) << 16) | ((unsigned)(v.w - b0) << 24);
  }
  stage_bn(y_in, stats_in, gam, bet, g, t, NMh, NMl, nullptr, nullptr);
  __syncthreads();

  f32x4 t0 = {0,0,0,0}, t1 = {0,0,0,0}, t2 = {0,0,0,0}, t3 = {0,0,0,0};
  f32x4 p0 = {0,0,0,0}, p1 = {0,0,0,0}, p2 = {0,0,0,0}, p3 = {0,0,0,0};
  const size_t wrow = (size_t)(w * 16 + ml) * 64 + kq * 8;
#pragma unroll
  for (int kt = 0; kt < 2; kt++) {
    bf16x8 ath = *(const bf16x8*)(twh + wrow + kt * 32);
    bf16x8 atl = *(const bf16x8*)(twl + wrow + kt * 32);
    bf16x8 aph = *(const bf16x8*)(pwh + wrow + kt * 32);
    bf16x8 apl = *(const bf16x8*)(pwl + wrow + kt * 32);
    int kk = kt * 32 + kq * 8;
#pragma unroll
    for (int nt = 0; nt < 4; nt++) {
      int node = nt * 16 + ml;
      bf16x8 bh = *(const bf16x8*)&NMh[XIDX(node, kk)];
      bf16x8 bl = *(const bf16x8*)&NMl[XIDX(node, kk)];
      f32x4& T = (nt == 0) ? t0 : (nt == 1) ? t1 : (nt == 2) ? t2 : t3;
      f32x4& P = (nt == 0) ? p0 : (nt == 1) ? p1 : (nt == 2) ? p2 : p3;
      T = MFMA(ath, bh, T); T = MFMA(atl, bh, T); T = MFMA(ath, bl, T);
      P = MFMA(aph, bh, P); P = MFMA(apl, bh, P); P = MFMA(aph, bl, P);
    }
  }
  // write T to LDS [node][ch], stride 68 (own-wave columns only)
#pragma unroll
  for (int nt = 0; nt < 4; nt++) {
    f32x4 T = (nt == 0) ? t0 : (nt == 1) ? t1 : (nt == 2) ? t2 : t3;
    int n = nt * 16 + ml;
    float4 v; v.x = T[0]; v.y = T[1]; v.z = T[2]; v.w = T[3];
    *(float4*)&Tf[n * 68 + w * 16 + kq * 4] = v;
  }
  // min-gather + epilogue (Tf rows all written by this wave; sW synced above)
  float4 tbv = *(const float4*)(tb + w * 16 + kq * 4);
  float4 pbv = *(const float4*)(pb + w * 16 + kq * 4);
  float s1[4] = {0, 0, 0, 0}, s2[4] = {0, 0, 0, 0};
#pragma unroll
  for (int nt = 0; nt < 4; nt++) {
    int n = nt * 16 + ml;
    unsigned w0 = sW[n * 4], w1 = sW[n * 4 + 1], w2 = sW[n * 4 + 2],
             w3 = sW[n * 4 + 3];
    float4 mn = {3.4e38f, 3.4e38f, 3.4e38f, 3.4e38f};
#pragma unroll
    for (int e = 0; e < 16; e++) {
      unsigned wd = (e < 4) ? w0 : (e < 8) ? w1 : (e < 12) ? w2 : w3;
      int s = (wd >> ((e & 3) * 8)) & 255;
      float4 tv = *(const float4*)&Tf[s * 68 + w * 16 + kq * 4];
      mn.x = fminf(mn.x, tv.x); mn.y = fminf(mn.y, tv.y);
      mn.z = fminf(mn.z, tv.z); mn.w = fminf(mn.w, tv.w);
    }
    f32x4 T = (nt == 0) ? t0 : (nt == 1) ? t1 : (nt == 2) ? t2 : t3;
    f32x4 P = (nt == 0) ? p0 : (nt == 1) ? p1 : (nt == 2) ? p2 : p3;
    float4 yv;
    yv.x = T[0] + P[0] + tbv.x + pbv.x - mn.x;
    yv.y = T[1] + P[1] + tbv.y + pbv.y - mn.y;
    yv.z = T[2] + P[2] + tbv.z + pbv.z - mn.z;
    yv.w = T[3] + P[3] + tbv.w + pbv.w - mn.w;
    *(float4*)(y_out + ((size_t)(g * 64 + n)) * 64 + w * 16 + kq * 4) = yv;
    s1[0] += yv.x; s2[0] += yv.x * yv.x;
    s1[1] += yv.y; s2[1] += yv.y * yv.y;
    s1[2] += yv.z; s2[2] += yv.z * yv.z;
    s1[3] += yv.w; s2[3] += yv.w * yv.w;
  }
#pragma unroll
  for (int i = 0; i < 4; i++) {
#pragma unroll
    for (int off = 1; off < 16; off <<= 1) {
      s1[i] += __shfl_xor(s1[i], off, 64);
      s2[i] += __shfl_xor(s2[i], off, 64);
    }
  }
  if (ml == 0) {
    int c = w * 16 + kq * 4;
#pragma unroll
    for (int i = 0; i < 4; i++) {
      atomicAdd(stats_out + c + i, s1[i]);
      atomicAdd(stats_out + 64 + c + i, s2[i]);
    }
  }
}

// ---------------------------------------------------------------------------
// cheb layer 1: input feat (FIN=16), X-concat padded to K=64.
// W folded+padded: cols [0..15]=W0-W2, [16..31]=W1, [32..47]=W2, [48..63]=0.
// ---------------------------------------------------------------------------
__global__ __launch_bounds__(256, 3) void k_cheb1(
    const float* __restrict__ feat, const int* __restrict__ src,
    const u16* __restrict__ wh, const u16* __restrict__ wl,
    const float* __restrict__ bias, float* __restrict__ y_out,
    float* __restrict__ stats_out) {
  __shared__ u16 NMh[4096], NMl[4096], Ch[4096], Cl[4096], Adj[4096];
  const int t = threadIdx.x, g = blockIdx.x;
  const int L = t & 63;
  const int w = __builtin_amdgcn_readfirstlane(t >> 6);
  const int ml = L & 15, kq = L >> 4;
  {  // stage X0 = feat: thread covers node t>>2, ch (t&3)*4..+3
    int n = t >> 2, c0 = (t & 3) * 4;
    float4 v = *(const float4*)(feat + (size_t)(g * 64 + n) * 16 + c0);
    u16 hh[4], ll[4];
    split2(v.x, hh[0], ll[0]); split2(v.y, hh[1], ll[1]);
    split2(v.z, hh[2], ll[2]); split2(v.w, hh[3], ll[3]);
    s16x4 vh, vl;
#pragma unroll
    for (int i = 0; i < 4; i++) { vh[i] = (short)hh[i]; vl[i] = (short)ll[i]; }
    *(s16x4*)&NMh[XIDX(n, c0)] = vh;
    *(s16x4*)&NMl[XIDX(n, c0)] = vl;
#pragma unroll
    for (int i = 0; i < 4; i++) {
      Ch[XIDX(c0 + i, n)] = hh[i];
      Cl[XIDX(c0 + i, n)] = ll[i];
    }
  }
  // zero NM pad cols 48..63; build Adj
  if (w == 0) {
    bf16x8 z = {0, 0, 0, 0, 0, 0, 0, 0};
    *(bf16x8*)&NMh[XIDX(L, 48)] = z;
    *(bf16x8*)&NMh[XIDX(L, 56)] = z;
  } else if (w == 1) {
    bf16x8 z = {0, 0, 0, 0, 0, 0, 0, 0};
    *(bf16x8*)&NMl[XIDX(L, 48)] = z;
    *(bf16x8*)&NMl[XIDX(L, 56)] = z;
  } else if (w == 3) {
    build_adj(src, g, L, Adj);
  }
  __syncthreads();

  // lap1: X1 = -C1*Adj*X0 (ch 0..15) -> NM cols 16..31, CM rows 16..31
  {
    f32x4 l0 = {0, 0, 0, 0};
#pragma unroll
    for (int kt = 0; kt < 2; kt++) {
      int kk = kt * 32 + kq * 8;
      bf16x8 aa = *(const bf16x8*)&Adj[XIDX(w * 16 + ml, kk)];
      bf16x8 bh = *(const bf16x8*)&Ch[XIDX(ml, kk)];
      bf16x8 bl = *(const bf16x8*)&Cl[XIDX(ml, kk)];
      l0 = MFMA(aa, bh, l0);
      l0 = MFMA(aa, bl, l0);
    }
    int r0 = w * 16 + kq * 4;
    u16 hh[4], ll[4];
#pragma unroll
    for (int i = 0; i < 4; i++) {
      split2(l0[i] * (-C1), hh[i], ll[i]);
      NMh[XIDX(r0 + i, 16 + ml)] = hh[i];
      NMl[XIDX(r0 + i, 16 + ml)] = ll[i];
    }
    s16x4 vh, vl;
#pragma unroll
    for (int i = 0; i < 4; i++) { vh[i] = (short)hh[i]; vl[i] = (short)ll[i]; }
    *(s16x4*)&Ch[XIDX(16 + ml, r0)] = vh;
    *(s16x4*)&Cl[XIDX(16 + ml, r0)] = vl;
  }
  __syncthreads();
  // lap2: Z2 = -2C1*Adj*X1 -> NM cols 32..47
  {
    f32x4 l0 = {0, 0, 0, 0};
#pragma unroll
    for (int kt = 0; kt < 2; kt++) {
      int kk = kt * 32 + kq * 8;
      bf16x8 aa = *(const bf16x8*)&Adj[XIDX(w * 16 + ml, kk)];
      bf16x8 bh = *(const bf16x8*)&Ch[XIDX(16 + ml, kk)];
      bf16x8 bl = *(const bf16x8*)&Cl[XIDX(16 + ml, kk)];
      l0 = MFMA(aa, bh, l0);
      l0 = MFMA(aa, bl, l0);
    }
    int r0 = w * 16 + kq * 4;
    u16 hh[4], ll[4];
#pragma unroll
    for (int i = 0; i < 4; i++) {
      split2(l0[i] * (-2.0f * C1), hh[i], ll[i]);
      NMh[XIDX(r0 + i, 32 + ml)] = hh[i];
      NMl[XIDX(r0 + i, 32 + ml)] = ll[i];
    }
  }
  __syncthreads();
  // Y = Xcat @ Wfold^T, K=64
  f32x4 acc0 = {0,0,0,0}, acc1 = {0,0,0,0}, acc2 = {0,0,0,0}, acc3 = {0,0,0,0};
  const u16* whp = wh + (size_t)(w * 16 + ml) * 64 + kq * 8;
  const u16* wlp = wl + (size_t)(w * 16 + ml) * 64 + kq * 8;
#pragma unroll
  for (int kt = 0; kt < 2; kt++) {
    bf16x8 ah = *(const bf16x8*)(whp + kt * 32);
    bf16x8 al = *(const bf16x8*)(wlp + kt * 32);
    int kk = kt * 32 + kq * 8;
#pragma unroll
    for (int nt = 0; nt < 4; nt++) {
      int node = nt * 16 + ml;
      bf16x8 bh = *(const bf16x8*)&NMh[XIDX(node, kk)];
      bf16x8 bl = *(const bf16x8*)&NMl[XIDX(node, kk)];
      f32x4& A = (nt == 0) ? acc0 : (nt == 1) ? acc1 : (nt == 2) ? acc2 : acc3;
      A = MFMA(ah, bh, A);
      A = MFMA(al, bh, A);
      A = MFMA(ah, bl, A);
    }
  }
  epilogue(acc0, acc1, acc2, acc3, bias, g, w, ml, kq, y_out, stats_out);
}

// ---------------------------------------------------------------------------
// Final BN+ReLU + mean-pool
// ---------------------------------------------------------------------------
__global__ __launch_bounds__(256, 4) void k_pool(
    const float* __restrict__ y_in, const float* __restrict__ stats_in,
    const float* __restrict__ gam, const float* __restrict__ bet,
    float* __restrict__ out) {
  int t = threadIdx.x, g = blockIdx.x;
  int n = t & 63;
  int cog = __builtin_amdgcn_readfirstlane(t >> 6);
  const float inv = 1.0f / (float)NN;
  const float* yr = y_in + ((size_t)(g * 64 + n)) * 64 + cog * 16;
  float sumv = 0.f;
#pragma unroll
  for (int q = 0; q < 4; q++) {
    float4 v = ((const float4*)yr)[q];
#pragma unroll
    for (int k = 0; k < 4; k++) {
      int j = q * 4 + k;
      int c = cog * 16 + j;
      float s1 = stats_in[c], s2 = stats_in[64 + c];
      float mu = s1 * inv;
      float var = fmaf(s2, inv, -mu * mu);
      float sc = gam[c] * rsqrtf(var + EPSF);
      float sh = fmaf(-mu, sc, bet[c]);
      float x = (k == 0) ? v.x : (k == 1) ? v.y : (k == 2) ? v.z : v.w;
      float h = fmaxf(fmaf(sc, x, sh), 0.f);
      float s = h;
#pragma unroll
      for (int off = 32; off >= 1; off >>= 1) s += __shfl_xor(s, off, 64);
      sumv = (n == j) ? s : sumv;
    }
  }
  if (n < 16) out[(size_t)g * 64 + cog * 16 + n] = sumv * (1.0f / 64.0f);
}

// ---------------------------------------------------------------------------
// Weight prep: fold recurrence (W0' = W0 - W2), pad, split to bf16 hi/lo.
// ---------------------------------------------------------------------------
__global__ void k_prep(const float* __restrict__ c1w, const float* __restrict__ c2w,
                       const float* __restrict__ c3w, const float* __restrict__ e1t,
                       const float* __restrict__ e1p, const float* __restrict__ e2t,
                       const float* __restrict__ e2p, u16* __restrict__ W1h,
                       u16* __restrict__ W1l, u16* __restrict__ W2h,
                       u16* __restrict__ W2l, u16* __restrict__ W3h,
                       u16* __restrict__ W3l, u16* __restrict__ T1h,
                       u16* __restrict__ T1l, u16* __restrict__ P1h,
                       u16* __restrict__ P1l, u16* __restrict__ T2h,
                       u16* __restrict__ T2l, u16* __restrict__ P2h,
                       u16* __restrict__ P2l) {
  int t0 = blockIdx.x * 256 + threadIdx.x;
  int stride = gridDim.x * 256;
  for (int i = t0; i < 4096; i += stride) {  // cheb1: 64 x 64 (K padded)
    int r = i >> 6, c = i & 63;
    float v = 0.f;
    if (c < 16) v = c1w[r * 48 + c] - c1w[r * 48 + 32 + c];
    else if (c < 48) v = c1w[r * 48 + c];
    u16 h, l; split2(v, h, l); W1h[i] = h; W1l[i] = l;
  }
  for (int i = t0; i < 12288; i += stride) {  // cheb2: 64 x 192
    int r = i / 192, c = i - r * 192;
    float v = (c < 64) ? c2w[r * 192 + c] - c2w[r * 192 + 128 + c]
                       : c2w[r * 192 + c];
    u16 h, l; split2(v, h, l); W2h[i] = h; W2l[i] = l;
  }
  for (int i = t0; i < 12288; i += stride) {  // cheb3
    int r = i / 192, c = i - r * 192;
    float v = (c < 64) ? c3w[r * 192 + c] - c3w[r * 192 + 128 + c]
                       : c3w[r * 192 + c];
    u16 h, l; split2(v, h, l); W3h[i] = h; W3l[i] = l;
  }
  for (int i = t0; i < 4096; i += stride) {
    u16 h, l;
    split2(e1t[i], h, l); T1h[i] = h; T1l[i] = l;
    split2(e1p[i], h, l); P1h[i] = h; P1l[i] = l;
    split2(e2t[i], h, l); T2h[i] = h; T2l[i] = l;
    split2(e2p[i], h, l); P2h[i] = h; P2l[i] = l;
  }
}

// ---------------------------------------------------------------------------
extern "C" void kernel_launch(void* const* d_in, const int* in_sizes, int n_in,
                              void* d_out, int out_size, void* d_ws,
                              size_t ws_size, hipStream_t stream) {
  const float* feat = (const float*)d_in[0];
  const int* src = (const int*)d_in[1];
  const float* cheb1_w = (const float*)d_in[4];
  const float* cheb1_b = (const float*)d_in[5];
  const float* bn1_g = (const float*)d_in[6];
  const float* bn1_b = (const float*)d_in[7];
  const float* e1_tw = (const float*)d_in[8];
  const float* e1_tb = (const float*)d_in[9];
  const float* e1_pw = (const float*)d_in[10];
  const float* e1_pb = (const float*)d_in[11];
  const float* bne1_g = (const float*)d_in[12];
  const float* bne1_b = (const float*)d_in[13];
  const float* cheb2_w = (const float*)d_in[14];
  const float* cheb2_b = (const float*)d_in[15];
  const float* bn2_g = (const float*)d_in[16];
  const float* bn2_b = (const float*)d_in[17];
  const float* e2_tw = (const float*)d_in[18];
  const float* e2_tb = (const float*)d_in[19];
  const float* e2_pw = (const float*)d_in[20];
  const float* e2_pb = (const float*)d_in[21];
  const float* bne2_g = (const float*)d_in[22];
  const float* bne2_b = (const float*)d_in[23];
  const float* cheb3_w = (const float*)d_in[24];
  const float* cheb3_b = (const float*)d_in[25];
  const float* bn3_g = (const float*)d_in[26];
  const float* bn3_b = (const float*)d_in[27];

  float* bufA = (float*)d_ws;
  float* bufB = bufA + (size_t)NN * HH;
  float* stats = bufB + (size_t)NN * HH;
  u16* wq = (u16*)(stats + 640);
  u16* W1h = wq;           u16* W1l = W1h + 4096;
  u16* W2h = W1l + 4096;   u16* W2l = W2h + 12288;
  u16* W3h = W2l + 12288;  u16* W3l = W3h + 12288;
  u16* T1h = W3l + 12288;  u16* T1l = T1h + 4096;
  u16* P1h = T1l + 4096;   u16* P1l = P1h + 4096;
  u16* T2h = P1l + 4096;   u16* T2l = T2h + 4096;
  u16* P2h = T2l + 4096;   u16* P2l = P2h + 4096;

  hipMemsetAsync(stats, 0, 640 * sizeof(float), stream);
  k_prep<<<16, 256, 0, stream>>>(cheb1_w, cheb2_w, cheb3_w, e1_tw, e1_pw,
                                 e2_tw, e2_pw, W1h, W1l, W2h, W2l, W3h, W3l,
                                 T1h, T1l, P1h, P1l, T2h, T2l, P2h, P2l);

  k_cheb1<<<NG, 256, 0, stream>>>(feat, src, W1h, W1l, cheb1_b, bufA, stats);
  k_econv<<<NG, 256, 0, stream>>>(bufA, stats, bn1_g, bn1_b, src, T1h, T1l,
                                  P1h, P1l, e1_tb, e1_pb, bufB, stats + 128);
  k_cheb64<<<NG, 256, 0, stream>>>(bufB, stats + 128, bne1_g, bne1_b, src, W2h,
                                   W2l, cheb2_b, bufA, stats + 256);
  k_econv<<<NG, 256, 0, stream>>>(bufA, stats + 256, bn2_g, bn2_b, src, T2h,
                                  T2l, P2h, P2l, e2_tb, e2_pb, bufB,
                                  stats + 384);
  k_cheb64<<<NG, 256, 0, stream>>>(bufB, stats + 384, bne2_g, bne2_b, src, W3h,
                                   W3l, cheb3_b, bufA, stats + 512);
  k_pool<<<NG, 256, 0, stream>>>(bufA, stats + 512, bn3_g, bn3_b,
                                 (float*)d_out);
}

// Round 3
// 231.895 us; speedup vs baseline: 2.8596x; 2.8596x over previous
//
#include <hip/hip_runtime.h>

#define NN 65536
#define PP 64
#define HH 64
#define FINN 16
#define NG 1024
#define EPSF 1e-5f
#define C1 0.0625f

typedef short bf16x8 __attribute__((ext_vector_type(8)));
typedef short s16x4 __attribute__((ext_vector_type(4)));
typedef float f32x4 __attribute__((ext_vector_type(4)));
typedef unsigned short u16;

#define MFMA(a, b, c) __builtin_amdgcn_mfma_f32_16x16x32_bf16(a, b, c, 0, 0, 0)

__device__ __forceinline__ u16 f2bf(float x) {
  union { float f; unsigned u; } v; v.f = x; return (u16)(v.u >> 16);
}
__device__ __forceinline__ float bf2f(u16 h) {
  union { float f; unsigned u; } v; v.u = ((unsigned)h) << 16; return v.f;
}
__device__ __forceinline__ void split2(float x, u16& h, u16& l) {
  h = f2bf(x); l = f2bf(x - bf2f(h));
}
// swizzled index into a 64x64 u16 LDS tile: 16B granules XOR'd by row&7
__device__ __forceinline__ int XIDX(int r, int c) {
  return r * 64 + ((((c >> 3) ^ (r & 7)) << 3) | (c & 7));
}

// Build local adjacency (multiplicity) for this graph into Adj (bf16, swizzled).
__device__ __forceinline__ void build_adj(const int* __restrict__ src, int g,
                                          int r, u16* Adj) {
  bf16x8 z = {0, 0, 0, 0, 0, 0, 0, 0};
#pragma unroll
  for (int q = 0; q < 8; q++) *(bf16x8*)&Adj[r * 64 + q * 8] = z;
  const int4* s4 = (const int4*)(src + (size_t)g * 1024 + (size_t)r * 16);
  int4 a0 = s4[0], a1 = s4[1], a2 = s4[2], a3 = s4[3];
  int b0 = g * 64;
  int ss[16] = {a0.x - b0, a0.y - b0, a0.z - b0, a0.w - b0,
                a1.x - b0, a1.y - b0, a1.z - b0, a1.w - b0,
                a2.x - b0, a2.y - b0, a2.z - b0, a2.w - b0,
                a3.x - b0, a3.y - b0, a3.z - b0, a3.w - b0};
#pragma unroll
  for (int e = 0; e < 16; e++) {
    int idx = XIDX(r, ss[e]);
    Adj[idx] = f2bf(bf2f(Adj[idx]) + 1.0f);
  }
}

// BN+ReLU stage from global pre-BN y into node-major (and optionally
// ch-major) split-bf16 LDS tiles. Thread covers node t>>2, ch (t&3)*16..+15.
__device__ __forceinline__ void stage_bn(
    const float* __restrict__ y_in, const float* __restrict__ stats_in,
    const float* __restrict__ gam, const float* __restrict__ bet, int g, int t,
    u16* NMh, u16* NMl, u16* CMh, u16* CMl) {
  const float inv = 1.0f / (float)NN;
  int n = t >> 2, c0 = (t & 3) * 16;
  const float* yr = y_in + ((size_t)(g * 64 + n)) * 64 + c0;
  u16 hh[16], ll[16];
#pragma unroll
  for (int q = 0; q < 4; q++) {
    float4 v = ((const float4*)yr)[q];
#pragma unroll
    for (int k = 0; k < 4; k++) {
      int c = c0 + q * 4 + k;
      float s1 = stats_in[c], s2 = stats_in[64 + c];
      float mu = s1 * inv;
      float var = fmaf(s2, inv, -mu * mu);
      float sc = gam[c] * rsqrtf(var + EPSF);
      float sh = fmaf(-mu, sc, bet[c]);
      float x = (k == 0) ? v.x : (k == 1) ? v.y : (k == 2) ? v.z : v.w;
      float h = fmaxf(fmaf(sc, x, sh), 0.f);
      split2(h, hh[q * 4 + k], ll[q * 4 + k]);
    }
  }
  bf16x8 vh0, vh1, vl0, vl1;
#pragma unroll
  for (int k = 0; k < 8; k++) {
    vh0[k] = (short)hh[k]; vl0[k] = (short)ll[k];
    vh1[k] = (short)hh[8 + k]; vl1[k] = (short)ll[8 + k];
  }
  *(bf16x8*)&NMh[XIDX(n, c0)] = vh0;
  *(bf16x8*)&NMh[XIDX(n, c0 + 8)] = vh1;
  *(bf16x8*)&NMl[XIDX(n, c0)] = vl0;
  *(bf16x8*)&NMl[XIDX(n, c0 + 8)] = vl1;
  if (CMh) {
#pragma unroll
    for (int k = 0; k < 16; k++) {
      CMh[XIDX(c0 + k, n)] = hh[k];
      CMl[XIDX(c0 + k, n)] = ll[k];
    }
  }
}

// Epilogue: add bias, store Yt frags as float4, store per-block BN partials
// (plain stores -- NO atomics; row g of `part` = [sum[64] | sumsq[64]]).
__device__ __forceinline__ void epilogue(f32x4 a0, f32x4 a1, f32x4 a2, f32x4 a3,
                                         const float* __restrict__ bias, int g,
                                         int w, int ml, int kq,
                                         float* __restrict__ y_out,
                                         float* __restrict__ part) {
  float4 bb = *(const float4*)(bias + w * 16 + kq * 4);
  float s1[4] = {0, 0, 0, 0}, s2[4] = {0, 0, 0, 0};
#pragma unroll
  for (int nt = 0; nt < 4; nt++) {
    f32x4 A = (nt == 0) ? a0 : (nt == 1) ? a1 : (nt == 2) ? a2 : a3;
    float4 yv;
    yv.x = A[0] + bb.x; yv.y = A[1] + bb.y;
    yv.z = A[2] + bb.z; yv.w = A[3] + bb.w;
    int n = nt * 16 + ml;
    *(float4*)(y_out + ((size_t)(g * 64 + n)) * 64 + w * 16 + kq * 4) = yv;
    s1[0] += yv.x; s2[0] += yv.x * yv.x;
    s1[1] += yv.y; s2[1] += yv.y * yv.y;
    s1[2] += yv.z; s2[2] += yv.z * yv.z;
    s1[3] += yv.w; s2[3] += yv.w * yv.w;
  }
#pragma unroll
  for (int i = 0; i < 4; i++) {
#pragma unroll
    for (int off = 1; off < 16; off <<= 1) {
      s1[i] += __shfl_xor(s1[i], off, 64);
      s2[i] += __shfl_xor(s2[i], off, 64);
    }
  }
  if (ml == 0) {
    float* pr = part + (size_t)g * 128 + w * 16 + kq * 4;
    *(float4*)pr = make_float4(s1[0], s1[1], s1[2], s1[3]);
    *(float4*)(pr + 64) = make_float4(s2[0], s2[1], s2[2], s2[3]);
  }
}

// ---------------------------------------------------------------------------
// Reduce 1024 x 128 per-block partials -> 128 final stats.
// Grid = 8 blocks; block b owns columns b*16 .. b*16+15.
// ---------------------------------------------------------------------------
__global__ __launch_bounds__(256) void k_reduce(const float* __restrict__ part,
                                                float* __restrict__ stats) {
  __shared__ float red[16 * 256];
  int b = blockIdx.x, t = threadIdx.x;
  float acc[16];
#pragma unroll
  for (int i = 0; i < 16; i++) acc[i] = 0.f;
#pragma unroll
  for (int rep = 0; rep < 4; rep++) {
    int g = rep * 256 + t;
    const float4* p = (const float4*)(part + (size_t)g * 128 + b * 16);
#pragma unroll
    for (int q = 0; q < 4; q++) {
      float4 v = p[q];
      acc[q * 4 + 0] += v.x; acc[q * 4 + 1] += v.y;
      acc[q * 4 + 2] += v.z; acc[q * 4 + 3] += v.w;
    }
  }
#pragma unroll
  for (int i = 0; i < 16; i++) red[i * 256 + t] = acc[i];
  __syncthreads();
  if (t < 128) {
#pragma unroll
    for (int i = 0; i < 16; i++) red[i * 256 + t] += red[i * 256 + t + 128];
  }
  __syncthreads();
  if (t < 64) {
#pragma unroll
    for (int i = 0; i < 16; i++) red[i * 256 + t] += red[i * 256 + t + 64];
  }
  __syncthreads();
  if (t < 16) {
    float s = 0.f;
#pragma unroll 8
    for (int k = 0; k < 64; k++) s += red[t * 256 + k];
    stats[b * 16 + t] = s;
  }
}

// ---------------------------------------------------------------------------
// cheb layer, CI=64 (layers 3 & 5). W is folded: [W0-W2 | W1 | W2], K=192.
// ---------------------------------------------------------------------------
__global__ __launch_bounds__(256, 2) void k_cheb64(
    const float* __restrict__ y_in, const float* __restrict__ stats_in,
    const float* __restrict__ gam, const float* __restrict__ bet,
    const int* __restrict__ src, const u16* __restrict__ wh,
    const u16* __restrict__ wl, const float* __restrict__ bias,
    float* __restrict__ y_out, float* __restrict__ part) {
  __shared__ u16 NMh[4096], NMl[4096], C0h[4096], C0l[4096], C1h[4096],
      C1l[4096], Adj[4096];
  const int t = threadIdx.x, g = blockIdx.x;
  const int L = t & 63;
  const int w = __builtin_amdgcn_readfirstlane(t >> 6);
  const int ml = L & 15, kq = L >> 4;

  stage_bn(y_in, stats_in, gam, bet, g, t, NMh, NMl, C0h, C0l);
  if (w == 3) build_adj(src, g, L, Adj);
  __syncthreads();

  f32x4 acc0 = {0, 0, 0, 0}, acc1 = {0, 0, 0, 0}, acc2 = {0, 0, 0, 0},
        acc3 = {0, 0, 0, 0};
  const u16* whp = wh + (size_t)(w * 16 + ml) * 192 + kq * 8;
  const u16* wlp = wl + (size_t)(w * 16 + ml) * 192 + kq * 8;

  auto yacc = [&](int kbase) {
#pragma unroll
    for (int kt = 0; kt < 2; kt++) {
      bf16x8 ah = *(const bf16x8*)(whp + kbase + kt * 32);
      bf16x8 al = *(const bf16x8*)(wlp + kbase + kt * 32);
      int kk = kt * 32 + kq * 8;
#pragma unroll
      for (int nt = 0; nt < 4; nt++) {
        int node = nt * 16 + ml;
        bf16x8 bh = *(const bf16x8*)&NMh[XIDX(node, kk)];
        bf16x8 bl = *(const bf16x8*)&NMl[XIDX(node, kk)];
        f32x4& A = (nt == 0) ? acc0 : (nt == 1) ? acc1 : (nt == 2) ? acc2 : acc3;
        A = MFMA(ah, bh, A);
        A = MFMA(al, bh, A);
        A = MFMA(ah, bl, A);
      }
    }
  };

  auto lap = [&](const u16* Bh, const u16* Bl, float scale, u16* oCh, u16* oCl) {
    f32x4 l0 = {0, 0, 0, 0}, l1 = {0, 0, 0, 0}, l2 = {0, 0, 0, 0},
          l3 = {0, 0, 0, 0};
#pragma unroll
    for (int kt = 0; kt < 2; kt++) {
      int kk = kt * 32 + kq * 8;
      bf16x8 aa = *(const bf16x8*)&Adj[XIDX(w * 16 + ml, kk)];
#pragma unroll
      for (int nt = 0; nt < 4; nt++) {
        bf16x8 bh = *(const bf16x8*)&Bh[XIDX(nt * 16 + ml, kk)];
        bf16x8 bl = *(const bf16x8*)&Bl[XIDX(nt * 16 + ml, kk)];
        f32x4& A = (nt == 0) ? l0 : (nt == 1) ? l1 : (nt == 2) ? l2 : l3;
        A = MFMA(aa, bh, A);
        A = MFMA(aa, bl, A);
      }
    }
    int r0 = w * 16 + kq * 4;
#pragma unroll
    for (int nt = 0; nt < 4; nt++) {
      f32x4 A = (nt == 0) ? l0 : (nt == 1) ? l1 : (nt == 2) ? l2 : l3;
      int c = nt * 16 + ml;
      u16 hh[4], ll[4];
#pragma unroll
      for (int i = 0; i < 4; i++) {
        split2(A[i] * scale, hh[i], ll[i]);
        NMh[XIDX(r0 + i, c)] = hh[i];
        NMl[XIDX(r0 + i, c)] = ll[i];
      }
      if (oCh) {
        s16x4 vh, vl;
#pragma unroll
        for (int i = 0; i < 4; i++) { vh[i] = (short)hh[i]; vl[i] = (short)ll[i]; }
        *(s16x4*)&oCh[XIDX(c, r0)] = vh;
        *(s16x4*)&oCl[XIDX(c, r0)] = vl;
      }
    }
  };

  yacc(0);                 // X0 against W0' = W0 - W2
  __syncthreads();
  lap(C0h, C0l, -C1, C1h, C1l);       // X1 = -C1*Adj*X0 -> NM, CM1
  __syncthreads();
  yacc(64);                // X1 against W1
  __syncthreads();
  lap(C1h, C1l, -2.0f * C1, nullptr, nullptr);  // Z2 = -2C1*Adj*X1 -> NM
  __syncthreads();
  yacc(128);               // Z2 against W2
  epilogue(acc0, acc1, acc2, acc3, bias, g, w, ml, kq, y_out, part);
}

// ---------------------------------------------------------------------------
// econv: y[n] = T[n] + P[n] + tb + pb - min_src T[src]
// ---------------------------------------------------------------------------
__global__ __launch_bounds__(256, 4) void k_econv(
    const float* __restrict__ y_in, const float* __restrict__ stats_in,
    const float* __restrict__ gam, const float* __restrict__ bet,
    const int* __restrict__ src, const u16* __restrict__ twh,
    const u16* __restrict__ twl, const u16* __restrict__ pwh,
    const u16* __restrict__ pwl, const float* __restrict__ tb,
    const float* __restrict__ pb, float* __restrict__ y_out,
    float* __restrict__ part) {
  __shared__ u16 NMh[4096], NMl[4096];
  __shared__ float Tf[64 * 68];
  __shared__ unsigned sW[256];
  const int t = threadIdx.x, g = blockIdx.x;
  const int L = t & 63;
  const int w = __builtin_amdgcn_readfirstlane(t >> 6);
  const int ml = L & 15, kq = L >> 4;
  {
    const int4* s4 = (const int4*)(src + (size_t)g * 1024);
    int4 v = s4[t];
    int b0 = g * 64;
    sW[t] = (unsigned)(v.x - b0) | ((unsigned)(v.y - b0) << 8) |
            ((unsigned)(v.z - b0) << 16) | ((unsigned)(v.w - b0) << 24);
  }
  stage_bn(y_in, stats_in, gam, bet, g, t, NMh, NMl, nullptr, nullptr);
  __syncthreads();

  f32x4 t0 = {0,0,0,0}, t1 = {0,0,0,0}, t2 = {0,0,0,0}, t3 = {0,0,0,0};
  f32x4 p0 = {0,0,0,0}, p1 = {0,0,0,0}, p2 = {0,0,0,0}, p3 = {0,0,0,0};
  const size_t wrow = (size_t)(w * 16 + ml) * 64 + kq * 8;
#pragma unroll
  for (int kt = 0; kt < 2; kt++) {
    bf16x8 ath = *(const bf16x8*)(twh + wrow + kt * 32);
    bf16x8 atl = *(const bf16x8*)(twl + wrow + kt * 32);
    bf16x8 aph = *(const bf16x8*)(pwh + wrow + kt * 32);
    bf16x8 apl = *(const bf16x8*)(pwl + wrow + kt * 32);
    int kk = kt * 32 + kq * 8;
#pragma unroll
    for (int nt = 0; nt < 4; nt++) {
      int node = nt * 16 + ml;
      bf16x8 bh = *(const bf16x8*)&NMh[XIDX(node, kk)];
      bf16x8 bl = *(const bf16x8*)&NMl[XIDX(node, kk)];
      f32x4& T = (nt == 0) ? t0 : (nt == 1) ? t1 : (nt == 2) ? t2 : t3;
      f32x4& P = (nt == 0) ? p0 : (nt == 1) ? p1 : (nt == 2) ? p2 : p3;
      T = MFMA(ath, bh, T); T = MFMA(atl, bh, T); T = MFMA(ath, bl, T);
      P = MFMA(aph, bh, P); P = MFMA(apl, bh, P); P = MFMA(aph, bl, P);
    }
  }
  // write T to LDS [node][ch], stride 68 (own-wave columns only)
#pragma unroll
  for (int nt = 0; nt < 4; nt++) {
    f32x4 T = (nt == 0) ? t0 : (nt == 1) ? t1 : (nt == 2) ? t2 : t3;
    int n = nt * 16 + ml;
    float4 v; v.x = T[0]; v.y = T[1]; v.z = T[2]; v.w = T[3];
    *(float4*)&Tf[n * 68 + w * 16 + kq * 4] = v;
  }
  // min-gather + epilogue (Tf rows all written by this wave; sW synced above)
  float4 tbv = *(const float4*)(tb + w * 16 + kq * 4);
  float4 pbv = *(const float4*)(pb + w * 16 + kq * 4);
  float s1[4] = {0, 0, 0, 0}, s2[4] = {0, 0, 0, 0};
#pragma unroll
  for (int nt = 0; nt < 4; nt++) {
    int n = nt * 16 + ml;
    unsigned w0 = sW[n * 4], w1 = sW[n * 4 + 1], w2 = sW[n * 4 + 2],
             w3 = sW[n * 4 + 3];
    float4 mn = {3.4e38f, 3.4e38f, 3.4e38f, 3.4e38f};
#pragma unroll
    for (int e = 0; e < 16; e++) {
      unsigned wd = (e < 4) ? w0 : (e < 8) ? w1 : (e < 12) ? w2 : w3;
      int s = (wd >> ((e & 3) * 8)) & 255;
      float4 tv = *(const float4*)&Tf[s * 68 + w * 16 + kq * 4];
      mn.x = fminf(mn.x, tv.x); mn.y = fminf(mn.y, tv.y);
      mn.z = fminf(mn.z, tv.z); mn.w = fminf(mn.w, tv.w);
    }
    f32x4 T = (nt == 0) ? t0 : (nt == 1) ? t1 : (nt == 2) ? t2 : t3;
    f32x4 P = (nt == 0) ? p0 : (nt == 1) ? p1 : (nt == 2) ? p2 : p3;
    float4 yv;
    yv.x = T[0] + P[0] + tbv.x + pbv.x - mn.x;
    yv.y = T[1] + P[1] + tbv.y + pbv.y - mn.y;
    yv.z = T[2] + P[2] + tbv.z + pbv.z - mn.z;
    yv.w = T[3] + P[3] + tbv.w + pbv.w - mn.w;
    *(float4*)(y_out + ((size_t)(g * 64 + n)) * 64 + w * 16 + kq * 4) = yv;
    s1[0] += yv.x; s2[0] += yv.x * yv.x;
    s1[1] += yv.y; s2[1] += yv.y * yv.y;
    s1[2] += yv.z; s2[2] += yv.z * yv.z;
    s1[3] += yv.w; s2[3] += yv.w * yv.w;
  }
#pragma unroll
  for (int i = 0; i < 4; i++) {
#pragma unroll
    for (int off = 1; off < 16; off <<= 1) {
      s1[i] += __shfl_xor(s1[i], off, 64);
      s2[i] += __shfl_xor(s2[i], off, 64);
    }
  }
  if (ml == 0) {
    float* pr = part + (size_t)g * 128 + w * 16 + kq * 4;
    *(float4*)pr = make_float4(s1[0], s1[1], s1[2], s1[3]);
    *(float4*)(pr + 64) = make_float4(s2[0], s2[1], s2[2], s2[3]);
  }
}

// ---------------------------------------------------------------------------
// cheb layer 1: input feat (FIN=16), X-concat padded to K=64.
// W folded+padded: cols [0..15]=W0-W2, [16..31]=W1, [32..47]=W2, [48..63]=0.
// ---------------------------------------------------------------------------
__global__ __launch_bounds__(256, 3) void k_cheb1(
    const float* __restrict__ feat, const int* __restrict__ src,
    const u16* __restrict__ wh, const u16* __restrict__ wl,
    const float* __restrict__ bias, float* __restrict__ y_out,
    float* __restrict__ part) {
  __shared__ u16 NMh[4096], NMl[4096], Ch[4096], Cl[4096], Adj[4096];
  const int t = threadIdx.x, g = blockIdx.x;
  const int L = t & 63;
  const int w = __builtin_amdgcn_readfirstlane(t >> 6);
  const int ml = L & 15, kq = L >> 4;
  {  // stage X0 = feat: thread covers node t>>2, ch (t&3)*4..+3
    int n = t >> 2, c0 = (t & 3) * 4;
    float4 v = *(const float4*)(feat + (size_t)(g * 64 + n) * 16 + c0);
    u16 hh[4], ll[4];
    split2(v.x, hh[0], ll[0]); split2(v.y, hh[1], ll[1]);
    split2(v.z, hh[2], ll[2]); split2(v.w, hh[3], ll[3]);
    s16x4 vh, vl;
#pragma unroll
    for (int i = 0; i < 4; i++) { vh[i] = (short)hh[i]; vl[i] = (short)ll[i]; }
    *(s16x4*)&NMh[XIDX(n, c0)] = vh;
    *(s16x4*)&NMl[XIDX(n, c0)] = vl;
#pragma unroll
    for (int i = 0; i < 4; i++) {
      Ch[XIDX(c0 + i, n)] = hh[i];
      Cl[XIDX(c0 + i, n)] = ll[i];
    }
  }
  // zero NM pad cols 48..63; build Adj
  if (w == 0) {
    bf16x8 z = {0, 0, 0, 0, 0, 0, 0, 0};
    *(bf16x8*)&NMh[XIDX(L, 48)] = z;
    *(bf16x8*)&NMh[XIDX(L, 56)] = z;
  } else if (w == 1) {
    bf16x8 z = {0, 0, 0, 0, 0, 0, 0, 0};
    *(bf16x8*)&NMl[XIDX(L, 48)] = z;
    *(bf16x8*)&NMl[XIDX(L, 56)] = z;
  } else if (w == 3) {
    build_adj(src, g, L, Adj);
  }
  __syncthreads();

  // lap1: X1 = -C1*Adj*X0 (ch 0..15) -> NM cols 16..31, CM rows 16..31
  {
    f32x4 l0 = {0, 0, 0, 0};
#pragma unroll
    for (int kt = 0; kt < 2; kt++) {
      int kk = kt * 32 + kq * 8;
      bf16x8 aa = *(const bf16x8*)&Adj[XIDX(w * 16 + ml, kk)];
      bf16x8 bh = *(const bf16x8*)&Ch[XIDX(ml, kk)];
      bf16x8 bl = *(const bf16x8*)&Cl[XIDX(ml, kk)];
      l0 = MFMA(aa, bh, l0);
      l0 = MFMA(aa, bl, l0);
    }
    int r0 = w * 16 + kq * 4;
    u16 hh[4], ll[4];
#pragma unroll
    for (int i = 0; i < 4; i++) {
      split2(l0[i] * (-C1), hh[i], ll[i]);
      NMh[XIDX(r0 + i, 16 + ml)] = hh[i];
      NMl[XIDX(r0 + i, 16 + ml)] = ll[i];
    }
    s16x4 vh, vl;
#pragma unroll
    for (int i = 0; i < 4; i++) { vh[i] = (short)hh[i]; vl[i] = (short)ll[i]; }
    *(s16x4*)&Ch[XIDX(16 + ml, r0)] = vh;
    *(s16x4*)&Cl[XIDX(16 + ml, r0)] = vl;
  }
  __syncthreads();
  // lap2: Z2 = -2C1*Adj*X1 -> NM cols 32..47
  {
    f32x4 l0 = {0, 0, 0, 0};
#pragma unroll
    for (int kt = 0; kt < 2; kt++) {
      int kk = kt * 32 + kq * 8;
      bf16x8 aa = *(const bf16x8*)&Adj[XIDX(w * 16 + ml, kk)];
      bf16x8 bh = *(const bf16x8*)&Ch[XIDX(16 + ml, kk)];
      bf16x8 bl = *(const bf16x8*)&Cl[XIDX(16 + ml, kk)];
      l0 = MFMA(aa, bh, l0);
      l0 = MFMA(aa, bl, l0);
    }
    int r0 = w * 16 + kq * 4;
    u16 hh[4], ll[4];
#pragma unroll
    for (int i = 0; i < 4; i++) {
      split2(l0[i] * (-2.0f * C1), hh[i], ll[i]);
      NMh[XIDX(r0 + i, 32 + ml)] = hh[i];
      NMl[XIDX(r0 + i, 32 + ml)] = ll[i];
    }
  }
  __syncthreads();
  // Y = Xcat @ Wfold^T, K=64
  f32x4 acc0 = {0,0,0,0}, acc1 = {0,0,0,0}, acc2 = {0,0,0,0}, acc3 = {0,0,0,0};
  const u16* whp = wh + (size_t)(w * 16 + ml) * 64 + kq * 8;
  const u16* wlp = wl + (size_t)(w * 16 + ml) * 64 + kq * 8;
#pragma unroll
  for (int kt = 0; kt < 2; kt++) {
    bf16x8 ah = *(const bf16x8*)(whp + kt * 32);
    bf16x8 al = *(const bf16x8*)(wlp + kt * 32);
    int kk = kt * 32 + kq * 8;
#pragma unroll
    for (int nt = 0; nt < 4; nt++) {
      int node = nt * 16 + ml;
      bf16x8 bh = *(const bf16x8*)&NMh[XIDX(node, kk)];
      bf16x8 bl = *(const bf16x8*)&NMl[XIDX(node, kk)];
      f32x4& A = (nt == 0) ? acc0 : (nt == 1) ? acc1 : (nt == 2) ? acc2 : acc3;
      A = MFMA(ah, bh, A);
      A = MFMA(al, bh, A);
      A = MFMA(ah, bl, A);
    }
  }
  epilogue(acc0, acc1, acc2, acc3, bias, g, w, ml, kq, y_out, part);
}

// ---------------------------------------------------------------------------
// Final BN+ReLU + mean-pool
// ---------------------------------------------------------------------------
__global__ __launch_bounds__(256, 4) void k_pool(
    const float* __restrict__ y_in, const float* __restrict__ stats_in,
    const float* __restrict__ gam, const float* __restrict__ bet,
    float* __restrict__ out) {
  int t = threadIdx.x, g = blockIdx.x;
  int n = t & 63;
  int cog = __builtin_amdgcn_readfirstlane(t >> 6);
  const float inv = 1.0f / (float)NN;
  const float* yr = y_in + ((size_t)(g * 64 + n)) * 64 + cog * 16;
  float sumv = 0.f;
#pragma unroll
  for (int q = 0; q < 4; q++) {
    float4 v = ((const float4*)yr)[q];
#pragma unroll
    for (int k = 0; k < 4; k++) {
      int j = q * 4 + k;
      int c = cog * 16 + j;
      float s1 = stats_in[c], s2 = stats_in[64 + c];
      float mu = s1 * inv;
      float var = fmaf(s2, inv, -mu * mu);
      float sc = gam[c] * rsqrtf(var + EPSF);
      float sh = fmaf(-mu, sc, bet[c]);
      float x = (k == 0) ? v.x : (k == 1) ? v.y : (k == 2) ? v.z : v.w;
      float h = fmaxf(fmaf(sc, x, sh), 0.f);
      float s = h;
#pragma unroll
      for (int off = 32; off >= 1; off >>= 1) s += __shfl_xor(s, off, 64);
      sumv = (n == j) ? s : sumv;
    }
  }
  if (n < 16) out[(size_t)g * 64 + cog * 16 + n] = sumv * (1.0f / 64.0f);
}

// ---------------------------------------------------------------------------
// Weight prep: fold recurrence (W0' = W0 - W2), pad, split to bf16 hi/lo.
// ---------------------------------------------------------------------------
__global__ void k_prep(const float* __restrict__ c1w, const float* __restrict__ c2w,
                       const float* __restrict__ c3w, const float* __restrict__ e1t,
                       const float* __restrict__ e1p, const float* __restrict__ e2t,
                       const float* __restrict__ e2p, u16* __restrict__ W1h,
                       u16* __restrict__ W1l, u16* __restrict__ W2h,
                       u16* __restrict__ W2l, u16* __restrict__ W3h,
                       u16* __restrict__ W3l, u16* __restrict__ T1h,
                       u16* __restrict__ T1l, u16* __restrict__ P1h,
                       u16* __restrict__ P1l, u16* __restrict__ T2h,
                       u16* __restrict__ T2l, u16* __restrict__ P2h,
                       u16* __restrict__ P2l) {
  int t0 = blockIdx.x * 256 + threadIdx.x;
  int stride = gridDim.x * 256;
  for (int i = t0; i < 4096; i += stride) {  // cheb1: 64 x 64 (K padded)
    int r = i >> 6, c = i & 63;
    float v = 0.f;
    if (c < 16) v = c1w[r * 48 + c] - c1w[r * 48 + 32 + c];
    else if (c < 48) v = c1w[r * 48 + c];
    u16 h, l; split2(v, h, l); W1h[i] = h; W1l[i] = l;
  }
  for (int i = t0; i < 12288; i += stride) {  // cheb2: 64 x 192
    int r = i / 192, c = i - r * 192;
    float v = (c < 64) ? c2w[r * 192 + c] - c2w[r * 192 + 128 + c]
                       : c2w[r * 192 + c];
    u16 h, l; split2(v, h, l); W2h[i] = h; W2l[i] = l;
  }
  for (int i = t0; i < 12288; i += stride) {  // cheb3
    int r = i / 192, c = i - r * 192;
    float v = (c < 64) ? c3w[r * 192 + c] - c3w[r * 192 + 128 + c]
                       : c3w[r * 192 + c];
    u16 h, l; split2(v, h, l); W3h[i] = h; W3l[i] = l;
  }
  for (int i = t0; i < 4096; i += stride) {
    u16 h, l;
    split2(e1t[i], h, l); T1h[i] = h; T1l[i] = l;
    split2(e1p[i], h, l); P1h[i] = h; P1l[i] = l;
    split2(e2t[i], h, l); T2h[i] = h; T2l[i] = l;
    split2(e2p[i], h, l); P2h[i] = h; P2l[i] = l;
  }
}

// ---------------------------------------------------------------------------
extern "C" void kernel_launch(void* const* d_in, const int* in_sizes, int n_in,
                              void* d_out, int out_size, void* d_ws,
                              size_t ws_size, hipStream_t stream) {
  const float* feat = (const float*)d_in[0];
  const int* src = (const int*)d_in[1];
  const float* cheb1_w = (const float*)d_in[4];
  const float* cheb1_b = (const float*)d_in[5];
  const float* bn1_g = (const float*)d_in[6];
  const float* bn1_b = (const float*)d_in[7];
  const float* e1_tw = (const float*)d_in[8];
  const float* e1_tb = (const float*)d_in[9];
  const float* e1_pw = (const float*)d_in[10];
  const float* e1_pb = (const float*)d_in[11];
  const float* bne1_g = (const float*)d_in[12];
  const float* bne1_b = (const float*)d_in[13];
  const float* cheb2_w = (const float*)d_in[14];
  const float* cheb2_b = (const float*)d_in[15];
  const float* bn2_g = (const float*)d_in[16];
  const float* bn2_b = (const float*)d_in[17];
  const float* e2_tw = (const float*)d_in[18];
  const float* e2_tb = (const float*)d_in[19];
  const float* e2_pw = (const float*)d_in[20];
  const float* e2_pb = (const float*)d_in[21];
  const float* bne2_g = (const float*)d_in[22];
  const float* bne2_b = (const float*)d_in[23];
  const float* cheb3_w = (const float*)d_in[24];
  const float* cheb3_b = (const float*)d_in[25];
  const float* bn3_g = (const float*)d_in[26];
  const float* bn3_b = (const float*)d_in[27];

  float* bufA = (float*)d_ws;
  float* bufB = bufA + (size_t)NN * HH;
  float* part = bufB + (size_t)NN * HH;            // 1024 x 128 partials
  float* stats = part + (size_t)NG * 128;          // 5 x 128 final stats
  u16* wq = (u16*)(stats + 5 * 128);
  u16* W1h = wq;           u16* W1l = W1h + 4096;
  u16* W2h = W1l + 4096;   u16* W2l = W2h + 12288;
  u16* W3h = W2l + 12288;  u16* W3l = W3h + 12288;
  u16* T1h = W3l + 12288;  u16* T1l = T1h + 4096;
  u16* P1h = T1l + 4096;   u16* P1l = P1h + 4096;
  u16* T2h = P1l + 4096;   u16* T2l = T2h + 4096;
  u16* P2h = T2l + 4096;   u16* P2l = P2h + 4096;

  k_prep<<<16, 256, 0, stream>>>(cheb1_w, cheb2_w, cheb3_w, e1_tw, e1_pw,
                                 e2_tw, e2_pw, W1h, W1l, W2h, W2l, W3h, W3l,
                                 T1h, T1l, P1h, P1l, T2h, T2l, P2h, P2l);

  k_cheb1<<<NG, 256, 0, stream>>>(feat, src, W1h, W1l, cheb1_b, bufA, part);
  k_reduce<<<8, 256, 0, stream>>>(part, stats + 0);
  k_econv<<<NG, 256, 0, stream>>>(bufA, stats + 0, bn1_g, bn1_b, src, T1h, T1l,
                                  P1h, P1l, e1_tb, e1_pb, bufB, part);
  k_reduce<<<8, 256, 0, stream>>>(part, stats + 128);
  k_cheb64<<<NG, 256, 0, stream>>>(bufB, stats + 128, bne1_g, bne1_b, src, W2h,
                                   W2l, cheb2_b, bufA, part);
  k_reduce<<<8, 256, 0, stream>>>(part, stats + 256);
  k_econv<<<NG, 256, 0, stream>>>(bufA, stats + 256, bn2_g, bn2_b, src, T2h,
                                  T2l, P2h, P2l, e2_tb, e2_pb, bufB, part);
  k_reduce<<<8, 256, 0, stream>>>(part, stats + 384);
  k_cheb64<<<NG, 256, 0, stream>>>(bufB, stats + 384, bne2_g, bne2_b, src, W3h,
                                   W3l, cheb3_b, bufA, part);
  k_reduce<<<8, 256, 0, stream>>>(part, stats + 512);
  k_pool<<<NG, 256, 0, stream>>>(bufA, stats + 512, bn3_g, bn3_b,
                                 (float*)d_out);
}